// Round 22
// baseline (625.226 us; speedup 1.0000x reference)
//
#include <hip/hip_runtime.h>

typedef __attribute__((ext_vector_type(8))) short short8;
typedef __attribute__((ext_vector_type(4))) float f32x4;
typedef __attribute__((ext_vector_type(16))) float f32x16;
typedef __attribute__((ext_vector_type(4))) unsigned short us4;

constexpr int NB = 8, NC = 256, IH = 64, IW = 96;
constexpr int PATCH = 21, RAD = 10;
constexpr int WIN = 28;                  // window j-width (tile j=8 + 20)
constexpr int KC = 32, NKS = NC / KC;    // channel chunking
constexpr int PLANE = IH * IW;
// 16x8 pixel tile, window 36 rows split into two 18-row halves per block
constexpr int NPOS = 512;                // 18*28=504 positions padded to 512
constexpr int NBCH = NPOS * 4;           // 2048 B-chunks / K-step
constexpr int NACH = 512;                // A: 128 px * 32ch / 8per-chunk
constexpr int NCHUNK = NBCH + NACH;      // 2560 chunks = 5 slots x 512 thr
constexpr int ASTR = IH * IW * KC;       // per-ks stride in x1k/x2k (unpadded)
constexpr size_t XT_ELEMS = (size_t)NB * NKS * ASTR;   // 12.58M per tensor
constexpr int GSTR = 129;                // G row stride (floats): bank stride 1
constexpr int XBLKS = NB * IH * 8;       // 4096 prepass blocks per tensor

__device__ __forceinline__ unsigned short f2bf(float f) {
  unsigned u = __builtin_bit_cast(unsigned, f);
  u += 0x7fffu + ((u >> 16) & 1u);       // RNE
  return (unsigned short)(u >> 16);
}

// ---- merged pre-pass (R20-validated): NCHW fp32 -> K-major bf16, both tensors
__global__ __launch_bounds__(256) void prepass_kmajor(
    const float* __restrict__ x1, const float* __restrict__ x2,
    unsigned short* __restrict__ x1k, unsigned short* __restrict__ x2k,
    unsigned short* __restrict__ zp) {
  __shared__ float lsf[32 * 97];
  const int t = threadIdx.x;
  if (blockIdx.x == 0 && t < 32) zp[t] = 0;   // 64B zero page, every launch
  const bool is2 = blockIdx.x >= XBLKS;
  const int blk = is2 ? (blockIdx.x - XBLKS) : blockIdx.x;   // b*512 + i*8 + ct
  const float* src = is2 ? x2 : x1;
  unsigned short* dst = is2 ? x2k : x1k;
  const int ct = blk & 7, i = (blk >> 3) & 63, b = blk >> 9;
  const int c0 = ct * 32;
  const float* sp = src + ((size_t)b * NC + c0) * PLANE + (size_t)i * IW;
#pragma unroll
  for (int k = 0; k < 3; ++k) {          // 768 float4
    int idx = k * 256 + t;
    int c = idx / 24, j4 = idx - c * 24;
    f32x4 v = *(const f32x4*)(sp + (size_t)c * PLANE + 4 * j4);
    float* lp = &lsf[c * 97 + 4 * j4];
    lp[0] = v[0]; lp[1] = v[1]; lp[2] = v[2]; lp[3] = v[3];
  }
  __syncthreads();
  unsigned short* dp = dst + (((size_t)(b * NKS + ct) * IH + i) * IW) * KC;
#pragma unroll
  for (int k = 0; k < 3; ++k) {          // 96 j x 8 cq -> contiguous 8B writes
    int o = k * 256 + t;
    int j = o >> 3, cq = o & 7;
    us4 v = {f2bf(lsf[(cq * 4 + 0) * 97 + j]), f2bf(lsf[(cq * 4 + 1) * 97 + j]),
             f2bf(lsf[(cq * 4 + 2) * 97 + j]), f2bf(lsf[(cq * 4 + 3) * 97 + j])};
    *(us4*)&dp[(size_t)j * KC + cq * 4] = v;
  }
}

// ---- main: R20 kernel with DOUBLE-buffered staging (80KB LDS) -> 2 blocks/CU
// = 2 independent barrier domains (the untested occupancy quadrant). Staging,
// swizzle, zero-page OOB, COMPUTE all R20-byte-identical; prefetch depth 2->1
// (depth proven null in R18); vmcnt re-derived: 5 loads/wave/stage, leave 5.
// Epilogue: 5 row-passes of 112 (fits 80KB; every diagonal run <= row 111).
__global__ __launch_bounds__(512, 4) void corr_half32d(
    const unsigned short* __restrict__ x1k, const unsigned short* __restrict__ x2k,
    const unsigned short* __restrict__ zp, float* __restrict__ out) {
  __shared__ __attribute__((aligned(16))) unsigned short ls[2 * NCHUNK * 8];  // 81920 B

  const int t = threadIdx.x, lane = t & 63, wv = t >> 6;   // wv 0..7
  const int bid = blockIdx.x;
  const int b = bid & 7;                 // batch -> XCD locality
  const int tile = bid >> 3;             // 0..95
  const int v = tile & 1;                // window half (rows 18v..18v+17)
  const int tt = tile >> 1;              // 0..47
  const int ti = tt / 12, tj = tt % 12;
  const int i0 = 16 * ti, j0 = 8 * tj;
  const int l31 = lane & 31, h2 = lane >> 5;

  const unsigned short* x1b = x1k + (size_t)b * NKS * ASTR;
  const unsigned short* x2b = x2k + (size_t)b * NKS * ASTR;

  // 5 stage slots x 512 thr (R20-validated): B swizzled, OOB/pad -> zero page
  const unsigned short* srcp[5];
  int sstp[5];
#pragma unroll
  for (int it = 0; it < 5; ++it) {
    int q = it * 512 + t;
    if (q < NBCH) {                       // B: invert slot swizzle (validated form)
      int w = ((q >> 3) << 1) | (((q >> 2) ^ (q >> 4)) & 1);
      int c4 = (q & 3) ^ (w & 3);
      bool pad = (w >= 504);
      int wd = pad ? 0 : w;
      int wi = wd / WIN, wj = wd - wi * WIN;
      int gi = i0 + 18 * v + wi - RAD;    // source row in unpadded x2
      int gj = j0 + wj - RAD;
      bool ok = !pad && ((unsigned)gi < (unsigned)IH) && ((unsigned)gj < (unsigned)IW);
      srcp[it] = ok ? (x2b + ((size_t)gi * IW + gj) * KC + c4 * 8) : zp;
      sstp[it] = ok ? ASTR : 0;
    } else {                              // A: same inverse over qa 0..511
      int qa = q - NBCH;
      int m = ((qa >> 3) << 1) | (((qa >> 2) ^ (qa >> 4)) & 1);
      int c4 = (qa & 3) ^ (m & 3);
      srcp[it] = x1b + ((size_t)(i0 + (m >> 3)) * IW + (j0 + (m & 7))) * KC + c4 * 8;
      sstp[it] = ASTR;
    }
  }

  f32x16 acc[2][4];
#pragma unroll
  for (int cc = 0; cc < 2; ++cc)
#pragma unroll
    for (int mt = 0; mt < 4; ++mt)
#pragma unroll
      for (int e = 0; e < 16; ++e) acc[cc][mt][e] = 0.f;

#define STAGE(BUF, KS)                                                              \
  {                                                                                 \
    unsigned short* lb = &ls[(BUF) * NCHUNK * 8];                                   \
    _Pragma("unroll")                                                               \
    for (int it = 0; it < 5; ++it)                                                  \
      __builtin_amdgcn_global_load_lds(                                             \
          (const void*)(srcp[it] + (size_t)(KS) * sstp[it]),                        \
          (void*)(lb + (it * 512 + wv * 64) * 8), 16, 0, 0);                        \
  }

// chunk(w,c4) at slot (4w+c4)^(w&7); A chunk(m,c4) at NBCH + ((4m+c4)^(m&7)).
// Per-lane k-slice identical for A and B (c4q = 2h + h2) -> dot product exact
// under any hw k-permutation (sigma argument, validated since R1).
#define COMPUTE(BUF)                                                                \
  {                                                                                 \
    const unsigned short* lb = &ls[(BUF) * NCHUNK * 8];                             \
    short8 afr[4][2];                                                               \
    _Pragma("unroll")                                                               \
    for (int mt = 0; mt < 4; ++mt)                                                  \
      _Pragma("unroll")                                                             \
      for (int h = 0; h < 2; ++h) {                                                 \
        int m = 32 * mt + l31, c4q = 2 * h + h2;                                    \
        afr[mt][h] = *(const short8*)(lb + (NBCH + ((4 * m + c4q) ^ (m & 7))) * 8); \
      }                                                                             \
    _Pragma("unroll")                                                               \
    for (int cc = 0; cc < 2; ++cc) {                                                \
      int wq = 32 * (2 * wv + cc) + l31;                                            \
      _Pragma("unroll")                                                             \
      for (int h = 0; h < 2; ++h) {                                                 \
        int c4q = 2 * h + h2;                                                       \
        short8 bf = *(const short8*)(lb + (((4 * wq + c4q) ^ (wq & 7))) * 8);       \
        _Pragma("unroll")                                                           \
        for (int mt = 0; mt < 4; ++mt)                                              \
          acc[cc][mt] = __builtin_amdgcn_mfma_f32_32x32x16_bf16(afr[mt][h], bf,     \
                                                                acc[cc][mt], 0, 0, 0); \
      }                                                                             \
    }                                                                               \
  }

  // prologue: stage ks=0
  STAGE(0, 0)

  // Validated ordering, double-buffered: issue stage(ks+1) (WAR: that buffer's
  // readers finished before the post-COMPUTE barrier of iter ks-1); counted
  // vmcnt leaves stage(ks+1)'s 5 -> drains own stage(ks); barrier -> all waves'
  // stage(ks) landed (RAW); compute; barrier protects buf restaged next iter.
#define ITER(KS, VM)                                           \
  if ((KS) < 7) STAGE(((KS) + 1) & 1, (KS) + 1)                \
  asm volatile("s_waitcnt vmcnt(" #VM ")" ::: "memory");       \
  asm volatile("s_barrier" ::: "memory");                      \
  COMPUTE((KS) & 1)                                            \
  asm volatile("s_barrier" ::: "memory");

  ITER(0, 5)
  ITER(1, 5)
  ITER(2, 5)
  ITER(3, 5)
  ITER(4, 5)
  ITER(5, 5)
  ITER(6, 5)
  ITER(7, 0)
#undef ITER
#undef COMPUTE
#undef STAGE

  // ---- epilogue: G transpose in 5 row-passes of 112 (=4x28; every 8-float
  // diagonal run rl0+7 <= 28*3+20+7 = 111 fits one pass). gf = 112*129*4 =
  // 57.8KB <= 80KB. 32x32 C/D mapping (m74/m101) as R19/R20.
  float* gf = (float*)ls;
#pragma unroll
  for (int p = 0; p < 5; ++p) {
    __syncthreads();                     // prior reads (staging or pass p-1) done
    const int R0 = 112 * p;
#pragma unroll
    for (int cc = 0; cc < 2; ++cc) {
      int n = 32 * (2 * wv + cc) + l31;
      if (n >= R0 && n < R0 + 112 && n < 504) {
        float* gr = &gf[(n - R0) * GSTR];
#pragma unroll
        for (int mt = 0; mt < 4; ++mt)
#pragma unroll
          for (int q = 0; q < 4; ++q) {
            float* gp = &gr[32 * mt + 8 * q + 4 * h2];
            gp[0] = acc[cc][mt][4 * q + 0];
            gp[1] = acc[cc][mt][4 * q + 1];
            gp[2] = acc[cc][mt][4 * q + 2];
            gp[3] = acc[cc][mt][4 * q + 3];
          }
      }
    }
    __syncthreads();
    // segment decode: local window rows wl = 4p+kk (kk 0..3, wl<18);
    // W = 18v + wl; c(W) = min(15,W)-max(0,W-20)+1 (ii count).
    int segs = 0;
#pragma unroll
    for (int kk = 0; kk < 4; ++kk) {
      int wl = 4 * p + kk;
      if (wl < 18) {
        int W = 18 * v + wl;
        int hi = W < 15 ? W : 15, lo = W - 20 > 0 ? W - 20 : 0;
        segs += hi - lo + 1;
      }
    }
    segs *= 21;
    for (int s = t; s < segs; s += 512) {
      int pidx = s / 21, pj = s - pidx * 21;
      int k = 0, rem = pidx, stop = 0;
#pragma unroll
      for (int kk = 0; kk < 3; ++kk) {
        int wl = 4 * p + kk;
        int W = 18 * v + wl;
        int hi = W < 15 ? W : 15, lo = W - 20 > 0 ? W - 20 : 0;
        int c = (wl < 18) ? (hi - lo + 1) : 0;
        int go = (!stop) && (c > 0) && (rem >= c);
        rem -= go ? c : 0;
        k += go;
        stop |= !go;
      }
      int W = 18 * v + 4 * p + k;
      int lo = W - 20 > 0 ? W - 20 : 0;
      int ii = lo + rem;
      int pi = W - ii;
      int rl0 = 28 * k + pj;
      float g[8];
#pragma unroll
      for (int e = 0; e < 8; ++e) g[e] = gf[(rl0 + e) * GSTR + 8 * ii + e];
      float* op = out + ((((size_t)b * PATCH + pi) * PATCH + pj) * IH + (i0 + ii)) * IW + j0;
      f32x4 v0 = {g[0], g[1], g[2], g[3]};
      f32x4 v1 = {g[4], g[5], g[6], g[7]};
      *(f32x4*)op = v0;
      *(f32x4*)(op + 4) = v1;
    }
  }
}

// ---------------- fallback (R1, validated): NCHW fp32 in-kernel ----------------
constexpr int LDKF = 40;
constexpr int NWINF = 784;
__global__ __launch_bounds__(512, 2) void corr_mfma_fb(
    const float* __restrict__ x1, const float* __restrict__ x2, float* __restrict__ out) {
  __shared__ __attribute__((aligned(16))) unsigned short lsA[64 * LDKF];
  __shared__ __attribute__((aligned(16))) unsigned short lsB[NWINF * LDKF];
  const int t = threadIdx.x;
  const int b = blockIdx.y;
  const int ti = blockIdx.x / 12, tj = blockIdx.x % 12;
  const int i0 = ti * 8, j0 = tj * 8;
  const int lane = t & 63, wv = t >> 6;
  const int mtp = wv >> 2, cg = wv & 3, cbeg = cg * 12;
  const int qk = lane >> 4, lr = lane & 15;
  f32x4 acc[2][13];
#pragma unroll
  for (int a = 0; a < 2; ++a)
#pragma unroll
    for (int cc = 0; cc < 13; ++cc) acc[a][cc] = (f32x4){0.f, 0.f, 0.f, 0.f};
  const int am = t & 63, ak4 = t >> 6;
  const int aii = am >> 3, ajj = am & 7;
  const float* x1p = x1 + ((size_t)b * NC + 4 * ak4) * PLANE + (size_t)(i0 + aii) * IW + (j0 + ajj);
  const float* x2b = x2 + (size_t)b * NC * PLANE;
  for (int ks = 0; ks < NKS; ++ks) {
    __syncthreads();
    {
      const float* p = x1p + (size_t)ks * KC * PLANE;
      us4 v = {f2bf(p[0]), f2bf(p[PLANE]), f2bf(p[2 * PLANE]), f2bf(p[3 * PLANE])};
      *(us4*)&lsA[am * LDKF + 4 * ak4] = v;
    }
    for (int w = t; w < NWINF; w += 512) {
      const int wi = w / WIN, wj = w - wi * WIN;
      const int gi = i0 - RAD + wi, gj = j0 - RAD + wj;
      const bool ok = ((unsigned)gi < (unsigned)IH) && ((unsigned)gj < (unsigned)IW);
      const float* p = x2b + ((size_t)(ks * KC) * IH + gi) * IW + gj;
      unsigned short* dst = &lsB[w * LDKF];
#pragma unroll
      for (int k4 = 0; k4 < 8; ++k4) {
        const float* q = p + (size_t)(4 * k4) * PLANE;
        us4 v = {f2bf(ok ? q[0] : 0.f), f2bf(ok ? q[PLANE] : 0.f),
                 f2bf(ok ? q[2 * PLANE] : 0.f), f2bf(ok ? q[3 * PLANE] : 0.f)};
        *(us4*)&dst[4 * k4] = v;
      }
    }
    __syncthreads();
    short8 a0 = *(const short8*)&lsA[(32 * mtp + lr) * LDKF + 8 * qk];
    short8 a1 = *(const short8*)&lsA[(32 * mtp + 16 + lr) * LDKF + 8 * qk];
#pragma unroll
    for (int cc = 0; cc < 13; ++cc) {
      const int wrow = 16 * (cbeg + cc) + lr;
      short8 bf = *(const short8*)&lsB[wrow * LDKF + 8 * qk];
      acc[0][cc] = __builtin_amdgcn_mfma_f32_16x16x32_bf16(a0, bf, acc[0][cc], 0, 0, 0);
      acc[1][cc] = __builtin_amdgcn_mfma_f32_16x16x32_bf16(a1, bf, acc[1][cc], 0, 0, 0);
    }
  }
#pragma unroll
  for (int a = 0; a < 2; ++a) {
    const int mb = 16 * (2 * mtp + a) + qk * 4;
#pragma unroll
    for (int cc = 0; cc < 13; ++cc) {
      if (cg > 0 && cc == 0) continue;
      const int n = 16 * (cbeg + cc) + lr;
      const int wi = n / WIN, wj = n - wi * WIN;
#pragma unroll
      for (int r = 0; r < 4; ++r) {
        const int m = mb + r;
        const int ii = m >> 3, jj = m & 7;
        const int pi = wi - ii, pj = wj - jj;
        if ((unsigned)pi < (unsigned)PATCH && (unsigned)pj < (unsigned)PATCH)
          out[((((size_t)b * PATCH + pi) * PATCH + pj) * IH + (i0 + ii)) * IW + (j0 + jj)] =
              acc[a][cc][r];
      }
    }
  }
}

extern "C" void kernel_launch(void* const* d_in, const int* in_sizes, int n_in,
                              void* d_out, int out_size, void* d_ws, size_t ws_size,
                              hipStream_t stream) {
  const float* x1 = (const float*)d_in[0];
  const float* x2 = (const float*)d_in[1];
  float* out = (float*)d_out;
  const size_t need = 2 * XT_ELEMS * sizeof(unsigned short) + 64;   // ~50.3 MB
  if (ws_size >= need) {
    unsigned short* x1k = (unsigned short*)d_ws;
    unsigned short* x2k = x1k + XT_ELEMS;
    unsigned short* zp = x2k + XT_ELEMS;   // 64B zero page
    prepass_kmajor<<<2 * XBLKS, 256, 0, stream>>>(x1, x2, x1k, x2k, zp);
    corr_half32d<<<NB * 96, 512, 0, stream>>>(x1k, x2k, zp, out);
  } else {
    dim3 grid(96, NB);
    corr_mfma_fb<<<grid, 512, 0, stream>>>(x1, x2, out);
  }
}

// Round 23
// 79.678 us; speedup vs baseline: 7.8469x; 7.8469x over previous
//
#include <hip/hip_runtime.h>

typedef __attribute__((ext_vector_type(8))) short short8;
typedef __attribute__((ext_vector_type(4))) float f32x4;
typedef __attribute__((ext_vector_type(16))) float f32x16;
typedef __attribute__((ext_vector_type(4))) unsigned short us4;

constexpr int NB = 8, NC = 256, IH = 64, IW = 96;
constexpr int PATCH = 21, RAD = 10;
constexpr int WIN = 28;                  // window j-width (tile j=8 + 20)
constexpr int KC = 32, NKS = NC / KC;    // channel chunking
constexpr int PLANE = IH * IW;
// 16x8 pixel tile, window 36 rows split into two 18-row halves per block
constexpr int NPOS = 512;                // 18*28=504 positions padded to 512
constexpr int NBCH = NPOS * 4;           // 2048 B-chunks / K-step
constexpr int NACH = 512;                // A: 128 px * 32ch / 8per-chunk
constexpr int NCHUNK = NBCH + NACH;      // 2560 chunks = 5 slots x 512 thr
constexpr int ASTR = IH * IW * KC;       // per-ks stride in x1k/x2k (unpadded)
constexpr size_t XT_ELEMS = (size_t)NB * NKS * ASTR;   // 12.58M per tensor
constexpr int GSTR = 129;                // G row stride (floats): bank stride 1
constexpr int XBLKS = NB * IH * 8;       // 4096 prepass blocks per tensor

__device__ __forceinline__ unsigned short f2bf(float f) {
  unsigned u = __builtin_bit_cast(unsigned, f);
  u += 0x7fffu + ((u >> 16) & 1u);       // RNE
  return (unsigned short)(u >> 16);
}

// ---- merged pre-pass (R20-validated): NCHW fp32 -> K-major bf16, both tensors
__global__ __launch_bounds__(256) void prepass_kmajor(
    const float* __restrict__ x1, const float* __restrict__ x2,
    unsigned short* __restrict__ x1k, unsigned short* __restrict__ x2k,
    unsigned short* __restrict__ zp) {
  __shared__ float lsf[32 * 97];
  const int t = threadIdx.x;
  if (blockIdx.x == 0 && t < 32) zp[t] = 0;   // 64B zero page, every launch
  const bool is2 = blockIdx.x >= XBLKS;
  const int blk = is2 ? (blockIdx.x - XBLKS) : blockIdx.x;   // b*512 + i*8 + ct
  const float* src = is2 ? x2 : x1;
  unsigned short* dst = is2 ? x2k : x1k;
  const int ct = blk & 7, i = (blk >> 3) & 63, b = blk >> 9;
  const int c0 = ct * 32;
  const float* sp = src + ((size_t)b * NC + c0) * PLANE + (size_t)i * IW;
#pragma unroll
  for (int k = 0; k < 3; ++k) {          // 768 float4
    int idx = k * 256 + t;
    int c = idx / 24, j4 = idx - c * 24;
    f32x4 v = *(const f32x4*)(sp + (size_t)c * PLANE + 4 * j4);
    float* lp = &lsf[c * 97 + 4 * j4];
    lp[0] = v[0]; lp[1] = v[1]; lp[2] = v[2]; lp[3] = v[3];
  }
  __syncthreads();
  unsigned short* dp = dst + (((size_t)(b * NKS + ct) * IH + i) * IW) * KC;
#pragma unroll
  for (int k = 0; k < 3; ++k) {          // 96 j x 8 cq -> contiguous 8B writes
    int o = k * 256 + t;
    int j = o >> 3, cq = o & 7;
    us4 v = {f2bf(lsf[(cq * 4 + 0) * 97 + j]), f2bf(lsf[(cq * 4 + 1) * 97 + j]),
             f2bf(lsf[(cq * 4 + 2) * 97 + j]), f2bf(lsf[(cq * 4 + 3) * 97 + j])};
    *(us4*)&dp[(size_t)j * KC + cq * 4] = v;
  }
}

// ---- main: R19/R20 kernel (best validated: main 61.8us, total 79.7us).
// Triple-buffered gload_lds, vmcnt-before-barrier, zero-page OOB, 32x32 MFMA.
__global__ __launch_bounds__(512, 2) void corr_half32(
    const unsigned short* __restrict__ x1k, const unsigned short* __restrict__ x2k,
    const unsigned short* __restrict__ zp, float* __restrict__ out) {
  __shared__ __attribute__((aligned(16))) unsigned short ls[3 * NCHUNK * 8];  // 122880 B

  const int t = threadIdx.x, lane = t & 63, wv = t >> 6;   // wv 0..7
  const int bid = blockIdx.x;
  const int b = bid & 7;                 // batch -> XCD locality
  const int tile = bid >> 3;             // 0..95
  const int v = tile & 1;                // window half (rows 18v..18v+17)
  const int tt = tile >> 1;              // 0..47
  const int ti = tt / 12, tj = tt % 12;
  const int i0 = 16 * ti, j0 = 8 * tj;
  const int l31 = lane & 31, h2 = lane >> 5;

  const unsigned short* x1b = x1k + (size_t)b * NKS * ASTR;
  const unsigned short* x2b = x2k + (size_t)b * NKS * ASTR;

  // 5 stage slots x 512 thr: slots 0-3 B (swizzled; OOB/pad -> zero page,
  // stride 0), slot 4 A. All addresses and strides are per-lane VGPRs.
  const unsigned short* srcp[5];
  int sstp[5];
#pragma unroll
  for (int it = 0; it < 5; ++it) {
    int q = it * 512 + t;
    if (q < NBCH) {                       // B: invert slot swizzle (validated form)
      int w = ((q >> 3) << 1) | (((q >> 2) ^ (q >> 4)) & 1);
      int c4 = (q & 3) ^ (w & 3);
      bool pad = (w >= 504);
      int wd = pad ? 0 : w;
      int wi = wd / WIN, wj = wd - wi * WIN;
      int gi = i0 + 18 * v + wi - RAD;    // source row in unpadded x2
      int gj = j0 + wj - RAD;
      bool ok = !pad && ((unsigned)gi < (unsigned)IH) && ((unsigned)gj < (unsigned)IW);
      srcp[it] = ok ? (x2b + ((size_t)gi * IW + gj) * KC + c4 * 8) : zp;
      sstp[it] = ok ? ASTR : 0;
    } else {                              // A: same inverse over qa 0..511
      int qa = q - NBCH;
      int m = ((qa >> 3) << 1) | (((qa >> 2) ^ (qa >> 4)) & 1);
      int c4 = (qa & 3) ^ (m & 3);
      srcp[it] = x1b + ((size_t)(i0 + (m >> 3)) * IW + (j0 + (m & 7))) * KC + c4 * 8;
      sstp[it] = ASTR;
    }
  }

  f32x16 acc[2][4];
#pragma unroll
  for (int cc = 0; cc < 2; ++cc)
#pragma unroll
    for (int mt = 0; mt < 4; ++mt)
#pragma unroll
      for (int e = 0; e < 16; ++e) acc[cc][mt][e] = 0.f;

#define STAGE(BUF, KS)                                                              \
  {                                                                                 \
    unsigned short* lb = &ls[(BUF) * NCHUNK * 8];                                   \
    _Pragma("unroll")                                                               \
    for (int it = 0; it < 5; ++it)                                                  \
      __builtin_amdgcn_global_load_lds(                                             \
          (const void*)(srcp[it] + (size_t)(KS) * sstp[it]),                        \
          (void*)(lb + (it * 512 + wv * 64) * 8), 16, 0, 0);                        \
  }

// chunk(w,c4) at slot (4w+c4)^(w&7); A chunk(m,c4) at NBCH + ((4m+c4)^(m&7)).
// Per-lane k-slice identical for A and B (c4q = 2h + h2) -> dot product exact
// under any hw k-permutation (sigma argument, validated since R1).
#define COMPUTE(BUF)                                                                \
  {                                                                                 \
    const unsigned short* lb = &ls[(BUF) * NCHUNK * 8];                             \
    short8 afr[4][2];                                                               \
    _Pragma("unroll")                                                               \
    for (int mt = 0; mt < 4; ++mt)                                                  \
      _Pragma("unroll")                                                             \
      for (int h = 0; h < 2; ++h) {                                                 \
        int m = 32 * mt + l31, c4q = 2 * h + h2;                                    \
        afr[mt][h] = *(const short8*)(lb + (NBCH + ((4 * m + c4q) ^ (m & 7))) * 8); \
      }                                                                             \
    _Pragma("unroll")                                                               \
    for (int cc = 0; cc < 2; ++cc) {                                                \
      int wq = 32 * (2 * wv + cc) + l31;                                            \
      _Pragma("unroll")                                                             \
      for (int h = 0; h < 2; ++h) {                                                 \
        int c4q = 2 * h + h2;                                                       \
        short8 bf = *(const short8*)(lb + (((4 * wq + c4q) ^ (wq & 7))) * 8);       \
        _Pragma("unroll")                                                           \
        for (int mt = 0; mt < 4; ++mt)                                              \
          acc[cc][mt] = __builtin_amdgcn_mfma_f32_32x32x16_bf16(afr[mt][h], bf,     \
                                                                acc[cc][mt], 0, 0, 0); \
      }                                                                             \
    }                                                                               \
  }

  // prologue: stage ks=0,1
  STAGE(0, 0)
  STAGE(1, 1)

  // R13/R19-validated ordering, uniform 5 loads/wave/stage: vmcnt(10) drains stage(ks).
#define ITER(KS, VM)                                           \
  if ((KS) < 6) STAGE(((KS) + 2) % 3, (KS) + 2)                \
  asm volatile("s_waitcnt vmcnt(" #VM ")" ::: "memory");       \
  asm volatile("s_barrier" ::: "memory");                      \
  COMPUTE((KS) % 3)                                            \
  asm volatile("s_barrier" ::: "memory");

  ITER(0, 10)
  ITER(1, 10)
  ITER(2, 10)
  ITER(3, 10)
  ITER(4, 10)
  ITER(5, 10)
  ITER(6, 5)
  ITER(7, 0)
#undef ITER
#undef COMPUTE
#undef STAGE

  // ---- epilogue: G transpose in 3 row-passes of 168 (R19/R20-validated) ----
  // 32x32 C/D (m74/m101): col=lane&31 -> position n; row=(reg&3)+8(reg>>2)+4*h2
  // -> pixel m. GSTR=129 -> bank stride 1: writes & diagonal gather conflict-free.
  float* gf = (float*)ls;
#pragma unroll
  for (int p = 0; p < 3; ++p) {
    __syncthreads();                     // prior reads (staging or pass p-1) done
    const int R0 = 168 * p;
#pragma unroll
    for (int cc = 0; cc < 2; ++cc) {
      int n = 32 * (2 * wv + cc) + l31;
      if (n >= R0 && n < R0 + 168 && n < 504) {
        float* gr = &gf[(n - R0) * GSTR];
#pragma unroll
        for (int mt = 0; mt < 4; ++mt)
#pragma unroll
          for (int q = 0; q < 4; ++q) {
            float* gp = &gr[32 * mt + 8 * q + 4 * h2];
            gp[0] = acc[cc][mt][4 * q + 0];
            gp[1] = acc[cc][mt][4 * q + 1];
            gp[2] = acc[cc][mt][4 * q + 2];
            gp[3] = acc[cc][mt][4 * q + 3];
          }
      }
    }
    __syncthreads();
    // segment decode (R13/R19-validated): W = pi+ii in [18v..18v+18)
    int segs = 0;
#pragma unroll
    for (int kk = 0; kk < 6; ++kk) {
      int W = 18 * v + 6 * p + kk;
      int hi = W < 15 ? W : 15, lo = W - 20 > 0 ? W - 20 : 0;
      segs += hi - lo + 1;
    }
    segs *= 21;
    for (int s = t; s < segs; s += 512) {
      int pidx = s / 21, pj = s - pidx * 21;
      int k = 0, rem = pidx, stop = 0;
#pragma unroll
      for (int kk = 0; kk < 5; ++kk) {
        int W = 18 * v + 6 * p + kk;
        int hi = W < 15 ? W : 15, lo = W - 20 > 0 ? W - 20 : 0;
        int c = hi - lo + 1;
        int go = (!stop) && (rem >= c);
        rem -= go ? c : 0;
        k += go;
        stop |= !go;
      }
      int W = 18 * v + 6 * p + k;
      int lo = W - 20 > 0 ? W - 20 : 0;
      int ii = lo + rem;
      int pi = W - ii;
      int rl0 = 28 * k + pj;
      float g[8];
#pragma unroll
      for (int e = 0; e < 8; ++e) g[e] = gf[(rl0 + e) * GSTR + 8 * ii + e];
      float* op = out + ((((size_t)b * PATCH + pi) * PATCH + pj) * IH + (i0 + ii)) * IW + j0;
      f32x4 v0 = {g[0], g[1], g[2], g[3]};
      f32x4 v1 = {g[4], g[5], g[6], g[7]};
      *(f32x4*)op = v0;
      *(f32x4*)(op + 4) = v1;
    }
  }
}

// ---------------- fallback (R1, validated): NCHW fp32 in-kernel ----------------
constexpr int LDKF = 40;
constexpr int NWINF = 784;
__global__ __launch_bounds__(512, 2) void corr_mfma_fb(
    const float* __restrict__ x1, const float* __restrict__ x2, float* __restrict__ out) {
  __shared__ __attribute__((aligned(16))) unsigned short lsA[64 * LDKF];
  __shared__ __attribute__((aligned(16))) unsigned short lsB[NWINF * LDKF];
  const int t = threadIdx.x;
  const int b = blockIdx.y;
  const int ti = blockIdx.x / 12, tj = blockIdx.x % 12;
  const int i0 = ti * 8, j0 = tj * 8;
  const int lane = t & 63, wv = t >> 6;
  const int mtp = wv >> 2, cg = wv & 3, cbeg = cg * 12;
  const int qk = lane >> 4, lr = lane & 15;
  f32x4 acc[2][13];
#pragma unroll
  for (int a = 0; a < 2; ++a)
#pragma unroll
    for (int cc = 0; cc < 13; ++cc) acc[a][cc] = (f32x4){0.f, 0.f, 0.f, 0.f};
  const int am = t & 63, ak4 = t >> 6;
  const int aii = am >> 3, ajj = am & 7;
  const float* x1p = x1 + ((size_t)b * NC + 4 * ak4) * PLANE + (size_t)(i0 + aii) * IW + (j0 + ajj);
  const float* x2b = x2 + (size_t)b * NC * PLANE;
  for (int ks = 0; ks < NKS; ++ks) {
    __syncthreads();
    {
      const float* p = x1p + (size_t)ks * KC * PLANE;
      us4 v = {f2bf(p[0]), f2bf(p[PLANE]), f2bf(p[2 * PLANE]), f2bf(p[3 * PLANE])};
      *(us4*)&lsA[am * LDKF + 4 * ak4] = v;
    }
    for (int w = t; w < NWINF; w += 512) {
      const int wi = w / WIN, wj = w - wi * WIN;
      const int gi = i0 - RAD + wi, gj = j0 - RAD + wj;
      const bool ok = ((unsigned)gi < (unsigned)IH) && ((unsigned)gj < (unsigned)IW);
      const float* p = x2b + ((size_t)(ks * KC) * IH + gi) * IW + gj;
      unsigned short* dst = &lsB[w * LDKF];
#pragma unroll
      for (int k4 = 0; k4 < 8; ++k4) {
        const float* q = p + (size_t)(4 * k4) * PLANE;
        us4 v = {f2bf(ok ? q[0] : 0.f), f2bf(ok ? q[PLANE] : 0.f),
                 f2bf(ok ? q[2 * PLANE] : 0.f), f2bf(ok ? q[3 * PLANE] : 0.f)};
        *(us4*)&dst[4 * k4] = v;
      }
    }
    __syncthreads();
    short8 a0 = *(const short8*)&lsA[(32 * mtp + lr) * LDKF + 8 * qk];
    short8 a1 = *(const short8*)&lsA[(32 * mtp + 16 + lr) * LDKF + 8 * qk];
#pragma unroll
    for (int cc = 0; cc < 13; ++cc) {
      const int wrow = 16 * (cbeg + cc) + lr;
      short8 bf = *(const short8*)&lsB[wrow * LDKF + 8 * qk];
      acc[0][cc] = __builtin_amdgcn_mfma_f32_16x16x32_bf16(a0, bf, acc[0][cc], 0, 0, 0);
      acc[1][cc] = __builtin_amdgcn_mfma_f32_16x16x32_bf16(a1, bf, acc[1][cc], 0, 0, 0);
    }
  }
#pragma unroll
  for (int a = 0; a < 2; ++a) {
    const int mb = 16 * (2 * mtp + a) + qk * 4;
#pragma unroll
    for (int cc = 0; cc < 13; ++cc) {
      if (cg > 0 && cc == 0) continue;
      const int n = 16 * (cbeg + cc) + lr;
      const int wi = n / WIN, wj = n - wi * WIN;
#pragma unroll
      for (int r = 0; r < 4; ++r) {
        const int m = mb + r;
        const int ii = m >> 3, jj = m & 7;
        const int pi = wi - ii, pj = wj - jj;
        if ((unsigned)pi < (unsigned)PATCH && (unsigned)pj < (unsigned)PATCH)
          out[((((size_t)b * PATCH + pi) * PATCH + pj) * IH + (i0 + ii)) * IW + (j0 + jj)] =
              acc[a][cc][r];
      }
    }
  }
}

extern "C" void kernel_launch(void* const* d_in, const int* in_sizes, int n_in,
                              void* d_out, int out_size, void* d_ws, size_t ws_size,
                              hipStream_t stream) {
  const float* x1 = (const float*)d_in[0];
  const float* x2 = (const float*)d_in[1];
  float* out = (float*)d_out;
  const size_t need = 2 * XT_ELEMS * sizeof(unsigned short) + 64;   // ~50.3 MB
  if (ws_size >= need) {
    unsigned short* x1k = (unsigned short*)d_ws;
    unsigned short* x2k = x1k + XT_ELEMS;
    unsigned short* zp = x2k + XT_ELEMS;   // 64B zero page
    prepass_kmajor<<<2 * XBLKS, 256, 0, stream>>>(x1, x2, x1k, x2k, zp);
    corr_half32<<<NB * 96, 512, 0, stream>>>(x1k, x2k, zp, out);
  } else {
    dim3 grid(96, NB);
    corr_mfma_fb<<<grid, 512, 0, stream>>>(x1, x2, out);
  }
}